// Round 9
// baseline (262.432 us; speedup 1.0000x reference)
//
#include <hip/hip_runtime.h>

// Causal Toeplitz-conv GEMM. y[b,h,n] = sum_{m<=n} u[b,h,m]*K[h,n-m] + D[h]*u[b,h,n]
// Out complex64 interleaved (re,0). Block=(h, 16 tiles of 128), 4 waves (2x2),
// wave 64x64 via 4x4 x v_mfma_f32_16x16x32_bf16.
// R9 = R6 structure + R7 KR2. The wall is the per-wave ds_read->MFMA chain
// (no pipe >40% busy; VALU/barrier cuts falsified twice, R4+R8). R6 bought
// 4 blocks/CU (VGPR 64 via same-step af[10], SLOTS=18, 39.4KB LDS) but lost
// it to KR8's L2 thrash (4.3MB/XCD); R7's KR2 (8.7MB total = 1.08MB/XCD,
// L2-resident; conv 205->161) fixes exactly that penalty. Combined: same-step
// A-loads are ~200cyc L2 hits hidden by 16 waves/CU.
// KR2: shift s=(m+1)&7 -> row s&1, byte offset -4*(s>>1) (4B-aligned loads,
// values identical: x'-(s&1) == x-s). u staged f32->bf16, load AFTER A (R1
// FIFO lesson), pack at post-compute commit. Tile -1's slot holds zeros.
// LDS row stride 136 shorts (conflict-minimal, measured 8.9e6 vs 6.1e7 at 128).

#define TILE 128
#define IGRP 16
#define SLOTS 18
#define BROW 136                        // shorts per (slot,b) row (128+8)
#define SLOT_STRIDE (8 * BROW)          // 1088 shorts
#define BS_SHORTS (SLOTS * SLOT_STRIDE) // 19584 shorts = 39168 B
#define KRC_STRIDE 264                  // tier0 LDS K row (shorts)
#define KRC_BUF (8 * KRC_STRIDE)        // 2112 shorts per buffer
#define EP_STRIDE 132

typedef short bf16x8 __attribute__((ext_vector_type(8)));
typedef float f32x4 __attribute__((ext_vector_type(4)));

__device__ __forceinline__ unsigned short f2bf(float f) {
    unsigned int u = __float_as_uint(f);
    u = (u + 0x7fffu + ((u >> 16) & 1u)) >> 16;  // RNE
    return (unsigned short)u;
}

// KR2[h][r][x] = bf16(K[h][L-1-(x-r)]) for x-r in [0,L), else 0.  r in 0..1.
__global__ __launch_bounds__(256) void build_KR2(
    const float* __restrict__ K, unsigned short* __restrict__ KR2, int L, int RS) {
    int x0 = (blockIdx.x * 256 + threadIdx.x) * 4;
    int r = blockIdx.y;
    long h = blockIdx.z;
    if (x0 >= RS) return;
    const float* Kh = K + h * (long)L;
    unsigned short s[4];
    #pragma unroll
    for (int j = 0; j < 4; ++j) {
        int t = x0 + j - r;
        s[j] = (t >= 0 && t < L) ? f2bf(Kh[L - 1 - t]) : (unsigned short)0;
    }
    uint2 w;
    w.x = s[0] | ((unsigned)s[1] << 16);
    w.y = s[2] | ((unsigned)s[3] << 16);
    *(uint2*)(KR2 + (h * 2 + r) * (long)RS + x0) = w;
}

// ---------------- tier1: A from global KR2 (L2-resident), 4 blocks/CU ----------------
__global__ __launch_bounds__(256, 4) void conv_main_t1(
    const float* __restrict__ u, const float* __restrict__ Dp,
    const unsigned short* __restrict__ KR2,
    float* __restrict__ outf, int H, int L, int G, int RS, int cplx, long out_floats)
{
    __shared__ __align__(16) char smem[BS_SHORTS * 2];
    unsigned short* Bs = (unsigned short*)smem;
    float* Ep = (float*)smem;

    const int tid  = threadIdx.x;
    const int lane = tid & 63;
    const int wv   = tid >> 6;
    const int wm   = wv >> 1;
    const int wn   = wv & 1;
    const int m    = lane & 15;
    const int quad = lane >> 4;

    const int bx = blockIdx.x;
    const int h  = bx % H;
    const int g  = (G - 1) - (bx / H);  // big groups first
    const int i0 = g * IGRP;
    const int dmax = i0 + IGRP - 1;

    const int rA = (m + 1) & 7;
    const int t0b = 127 - wm * 64 - m + quad * 8;   // t0 base (rb=0,kc=0)
    const int cB = (m & 7) * BROW + quad * 8;       // shorts

    // A source: byte addr into KR2, slides -256 B per step.
    // Shift rA -> row rA&1, byte offset -4*(rA>>1) (value at x' in row rA&1
    // equals K[L-1-(x-rA)] since x'-(rA&1) == x-rA).
    const char* pA = (const char*)(KR2 + ((long)(h * 2 + (rA & 1))) * RS)
                   + 2 * ((long)(L - TILE) + t0b + rA) - 4 * (rA >> 1);

    // B staging: one (b-row, 4-float) chunk per thread
    const int bb = tid >> 5;
    const int q8 = (tid & 31) * 4;
    const long ubase = ((long)bb * H + h) * L;

    f32x4 acc[4][4];
    {
        f32x4 z = {0.f, 0.f, 0.f, 0.f};
        #pragma unroll
        for (int a = 0; a < 4; ++a)
            #pragma unroll
            for (int b = 0; b < 4; ++b) acc[a][b] = z;
    }

    int sc4[4];
    #pragma unroll
    for (int nb = 0; nb < 4; ++nb) {
        int il = wn * 8 + nb * 2 + (m >> 3);
        sc4[nb] = (i0 + il) % SLOTS;
    }

    // ---- prologue: stage 17 window tiles (i0-1 .. i0+15), zeros for j<0 ----
    #pragma unroll
    for (int batch = 0; batch < 2; ++batch) {
        const int bn = batch ? 9 : 8;
        uint2 a8[9];
        #pragma unroll
        for (int q = 0; q < 9; ++q) {
            if (q < bn) {
                int j = i0 - 1 + batch * 8 + q;
                float4 v = {0.f, 0.f, 0.f, 0.f};
                if (j >= 0) v = *(const float4*)(u + ubase + (long)j * TILE + q8);
                a8[q].x = f2bf(v.x) | ((unsigned)f2bf(v.y) << 16);
                a8[q].y = f2bf(v.z) | ((unsigned)f2bf(v.w) << 16);
            }
        }
        #pragma unroll
        for (int q = 0; q < 9; ++q) {
            if (q < bn) {
                int j = i0 - 1 + batch * 8 + q;
                int sl = (j >= 0) ? (j % SLOTS) : (SLOTS - 1);
                *(uint2*)(Bs + sl * SLOT_STRIDE + bb * BROW + q8) = a8[q];
            }
        }
    }
    __syncthreads();

    bf16x8 af[10];

    // ---- main loop: one barrier per step ----
    int slotw = ((i0 - 1) % SLOTS + SLOTS) % SLOTS;
    for (int d = 0; d <= dmax; ++d) {
        const int jn = i0 - 1 - d;

        // all 10 A frags, same step (L2-resident KR2, ~200cyc; hidden by
        // 16 waves/CU — the reg diet that buys the 4th block)
        #pragma unroll
        for (int o = 0; o < 10; ++o) af[o] = *(const bf16x8*)(pA + (o - 3) * 32);

        // u load for this step's commit — AFTER A in the VM FIFO (R1 lesson)
        float4 fv = {0.f, 0.f, 0.f, 0.f};
        if (jn >= 0)
            fv = *(const float4*)(u + ubase + (long)jn * TILE + q8);

        // ---- compute ----
        const int dlim = d - i0;
        const unsigned short* Bp[4];
        #pragma unroll
        for (int nb = 0; nb < 4; ++nb)
            Bp[nb] = Bs + sc4[nb] * SLOT_STRIDE + cB;

        __builtin_amdgcn_s_setprio(1);
        #pragma unroll
        for (int kc = 0; kc < 4; ++kc) {
            #pragma unroll
            for (int nb = 0; nb < 4; ++nb) {
                const int nbg = wn * 4 + nb;
                if (2 * nbg + 1 >= dlim) {
                    // boundary tile -1 handled by zero-slot (slot 17 holds zeros)
                    bf16x8 bfr = *(const bf16x8*)(Bp[nb] + kc * 32);
                    acc[0][nb] = __builtin_amdgcn_mfma_f32_16x16x32_bf16(af[3 + 2 * kc], bfr, acc[0][nb], 0, 0, 0);
                    acc[1][nb] = __builtin_amdgcn_mfma_f32_16x16x32_bf16(af[2 + 2 * kc], bfr, acc[1][nb], 0, 0, 0);
                    acc[2][nb] = __builtin_amdgcn_mfma_f32_16x16x32_bf16(af[1 + 2 * kc], bfr, acc[2][nb], 0, 0, 0);
                    acc[3][nb] = __builtin_amdgcn_mfma_f32_16x16x32_bf16(af[0 + 2 * kc], bfr, acc[3][nb], 0, 0, 0);
                }
            }
        }
        __builtin_amdgcn_s_setprio(0);

        // commit (pack behind the MFMAs); jn==-1 commits ZEROS to slot 17
        if (jn >= -1) {
            uint2 bv;
            bv.x = f2bf(fv.x) | ((unsigned)f2bf(fv.y) << 16);
            bv.y = f2bf(fv.z) | ((unsigned)f2bf(fv.w) << 16);
            *(uint2*)(Bs + slotw * SLOT_STRIDE + bb * BROW + q8) = bv;
        }

        slotw = slotw ? slotw - 1 : SLOTS - 1;
        #pragma unroll
        for (int nb = 0; nb < 4; ++nb)
            sc4[nb] = sc4[nb] ? sc4[nb] - 1 : SLOTS - 1;
        pA -= 256;
        __syncthreads();
    }

    // ---- epilogue: LDS transpose (2 passes), skip-add, store ----
    const float Dh = Dp[h];
    const int ec = tid >> 2;
    const int ps = (tid & 3) * 32;
    #pragma unroll
    for (int pass = 0; pass < 2; ++pass) {
        if (wn == pass) {
            #pragma unroll
            for (int rb = 0; rb < 4; ++rb) {
                int p = wm * 64 + rb * 16 + quad * 4;  // C/D row = quad*4+reg
                #pragma unroll
                for (int nb = 0; nb < 4; ++nb) {
                    int cloc = nb * 16 + m;            // C/D col = lane&15
                    *(f32x4*)(Ep + cloc * EP_STRIDE + p) = acc[rb][nb];
                }
            }
        }
        __syncthreads();
        {
            int cg = pass * 64 + ec;
            int b  = cg & 7;
            int i  = i0 + (cg >> 3);
            long base = ((long)b * H + h) * L + (long)i * TILE + ps;
            const float* ep = Ep + ec * EP_STRIDE + ps;
            const float* us = u + base;
            if (cplx) {
                if (2 * (base + 32) <= out_floats) {
                    float4* o = (float4*)(outf + 2 * base);
                    #pragma unroll
                    for (int k4 = 0; k4 < 8; ++k4) {
                        float4 uv = ((const float4*)us)[k4];
                        float4 ev = *(const float4*)(ep + k4 * 4);
                        float4 o1, o2;
                        o1.x = ev.x + Dh * uv.x; o1.y = 0.f;
                        o1.z = ev.y + Dh * uv.y; o1.w = 0.f;
                        o2.x = ev.z + Dh * uv.z; o2.y = 0.f;
                        o2.z = ev.w + Dh * uv.w; o2.w = 0.f;
                        o[k4 * 2]     = o1;
                        o[k4 * 2 + 1] = o2;
                    }
                }
            } else {
                if (base + 32 <= out_floats) {
                    float4* o = (float4*)(outf + base);
                    #pragma unroll
                    for (int k4 = 0; k4 < 8; ++k4) {
                        float4 uv = ((const float4*)us)[k4];
                        float4 ev = *(const float4*)(ep + k4 * 4);
                        float4 ov;
                        ov.x = ev.x + Dh * uv.x;
                        ov.y = ev.y + Dh * uv.y;
                        ov.z = ev.z + Dh * uv.z;
                        ov.w = ev.w + Dh * uv.w;
                        o[k4] = ov;
                    }
                }
            }
        }
        __syncthreads();
    }
}

// ---------------- tier0 fallback: K staged from Kc via LDS (unused when ws fits) ----------------
__global__ __launch_bounds__(256, 3) void conv_main_t0(
    const float* __restrict__ u, const float* __restrict__ Kc,
    const float* __restrict__ Dp,
    float* __restrict__ outf, int H, int L, int G, int cplx, long out_floats)
{
    __shared__ __align__(16) char smem[BS_SHORTS * 2 + 2 * KRC_BUF * 2];
    unsigned short* Bs = (unsigned short*)smem;
    unsigned short* Krc = (unsigned short*)(smem + BS_SHORTS * 2);
    float* Ep = (float*)smem;

    const int tid  = threadIdx.x;
    const int lane = tid & 63;
    const int wv   = tid >> 6;
    const int wm   = wv >> 1;
    const int wn   = wv & 1;
    const int m    = lane & 15;
    const int quad = lane >> 4;

    const int bx = blockIdx.x;
    const int h  = bx % H;
    const int g  = (G - 1) - (bx / H);
    const int i0 = g * IGRP;
    const int dmax = i0 + IGRP - 1;

    const int rA = (m + 1) & 7;
    const int t0b = 127 - wm * 64 - m + quad * 8;
    const int cB = (m & 7) * BROW + quad * 8;
    const int cAb = 2 * (rA * KRC_STRIDE + t0b + rA);

    int ldsK[5], taK[5];
    bool vK[5];
    #pragma unroll
    for (int p = 0; p < 5; ++p) {
        int wi = tid + p * 256;
        vK[p] = wi < 1056;
        int rp = vK[p] ? (wi / 132) : 0;
        int tp = (wi - rp * 132) * 2;
        ldsK[p] = rp * KRC_STRIDE + tp;
        taK[p] = vK[p] ? (tp - rp) : -1000;
    }
    const float* Kfrow = Kc + (long)h * L;

    const int bb = tid >> 5;
    const int q8 = (tid & 31) * 4;
    const long ubase = ((long)bb * H + h) * L;

    f32x4 acc[4][4];
    {
        f32x4 z = {0.f, 0.f, 0.f, 0.f};
        #pragma unroll
        for (int a = 0; a < 4; ++a)
            #pragma unroll
            for (int b = 0; b < 4; ++b) acc[a][b] = z;
    }

    int sc4[4];
    #pragma unroll
    for (int nb = 0; nb < 4; ++nb) {
        int il = wn * 8 + nb * 2 + (m >> 3);
        sc4[nb] = (i0 + il) % SLOTS;
    }

    #pragma unroll
    for (int batch = 0; batch < 2; ++batch) {
        const int bn = batch ? 9 : 8;
        uint2 a8[9];
        #pragma unroll
        for (int q = 0; q < 9; ++q) {
            if (q < bn) {
                int j = i0 - 1 + batch * 8 + q;
                float4 v = {0.f, 0.f, 0.f, 0.f};
                if (j >= 0) v = *(const float4*)(u + ubase + (long)j * TILE + q8);
                a8[q].x = f2bf(v.x) | ((unsigned)f2bf(v.y) << 16);
                a8[q].y = f2bf(v.z) | ((unsigned)f2bf(v.w) << 16);
            }
        }
        #pragma unroll
        for (int q = 0; q < 9; ++q) {
            if (q < bn) {
                int j = i0 - 1 + batch * 8 + q;
                int sl = (j >= 0) ? (j % SLOTS) : (SLOTS - 1);
                *(uint2*)(Bs + sl * SLOT_STRIDE + bb * BROW + q8) = a8[q];
            }
        }
    }
    {
        #pragma unroll
        for (int p = 0; p < 5; ++p) {
            if (vK[p]) {
                unsigned int s0 = 0, s1 = 0;
                int ta = taK[p];
                int ka = 127 - ta;
                if (ta >= 0 && ta < 256 && ka >= 0) s0 = f2bf(Kfrow[ka]);
                if (ta + 1 >= 0 && ta + 1 < 256 && (ka - 1) >= 0) s1 = f2bf(Kfrow[ka - 1]);
                *(unsigned int*)(Krc + ldsK[p]) = s0 | (s1 << 16);
            }
        }
    }
    bf16x8 af[10];
    __syncthreads();

    int slotw = ((i0 - 1) % SLOTS + SLOTS) % SLOTS;
    for (int d = 0; d <= dmax; ++d) {
        const int dn = d + 1;
        const int jn = i0 - 1 - d;

        const char* Ab = (const char*)Krc + (d & 1) * (KRC_BUF * 2) + cAb;
        #pragma unroll
        for (int o = 0; o < 10; ++o) af[o] = *(const bf16x8*)(Ab + (o - 3) * 32);

        float4 fv = {0.f, 0.f, 0.f, 0.f};
        if (jn >= 0)
            fv = *(const float4*)(u + ubase + (long)jn * TILE + q8);

        unsigned int kv[5] = {0u, 0u, 0u, 0u, 0u};
        if (dn <= dmax) {
            #pragma unroll
            for (int p = 0; p < 5; ++p) {
                unsigned int s0 = 0, s1 = 0;
                int ta = taK[p];
                if (vK[p]) {
                    int ka = dn * TILE + 127 - ta;
                    if (ta >= 0 && ta < 256 && ka >= 0) s0 = f2bf(Kfrow[ka]);
                    if (ta + 1 >= 0 && ta + 1 < 256 && (ka - 1) >= 0) s1 = f2bf(Kfrow[ka - 1]);
                }
                kv[p] = s0 | (s1 << 16);
            }
        }

        const int dlim = d - i0;
        const unsigned short* Bp[4];
        #pragma unroll
        for (int nb = 0; nb < 4; ++nb)
            Bp[nb] = Bs + sc4[nb] * SLOT_STRIDE + cB;

        __builtin_amdgcn_s_setprio(1);
        #pragma unroll
        for (int kc = 0; kc < 4; ++kc) {
            #pragma unroll
            for (int nb = 0; nb < 4; ++nb) {
                const int nbg = wn * 4 + nb;
                if (2 * nbg + 1 >= dlim) {
                    bf16x8 bfr = *(const bf16x8*)(Bp[nb] + kc * 32);
                    acc[0][nb] = __builtin_amdgcn_mfma_f32_16x16x32_bf16(af[3 + 2 * kc], bfr, acc[0][nb], 0, 0, 0);
                    acc[1][nb] = __builtin_amdgcn_mfma_f32_16x16x32_bf16(af[2 + 2 * kc], bfr, acc[1][nb], 0, 0, 0);
                    acc[2][nb] = __builtin_amdgcn_mfma_f32_16x16x32_bf16(af[1 + 2 * kc], bfr, acc[2][nb], 0, 0, 0);
                    acc[3][nb] = __builtin_amdgcn_mfma_f32_16x16x32_bf16(af[0 + 2 * kc], bfr, acc[3][nb], 0, 0, 0);
                }
            }
        }
        __builtin_amdgcn_s_setprio(0);

        if (dn <= dmax) {
            unsigned short* Kw = Krc + (dn & 1) * KRC_BUF;
            #pragma unroll
            for (int p = 0; p < 5; ++p)
                if (vK[p]) *(unsigned int*)(Kw + ldsK[p]) = kv[p];
        }
        if (jn >= -1) {
            uint2 bv;
            bv.x = f2bf(fv.x) | ((unsigned)f2bf(fv.y) << 16);
            bv.y = f2bf(fv.z) | ((unsigned)f2bf(fv.w) << 16);
            *(uint2*)(Bs + slotw * SLOT_STRIDE + bb * BROW + q8) = bv;
        }

        slotw = slotw ? slotw - 1 : SLOTS - 1;
        #pragma unroll
        for (int nb = 0; nb < 4; ++nb)
            sc4[nb] = sc4[nb] ? sc4[nb] - 1 : SLOTS - 1;
        __syncthreads();
    }

    const float Dh = Dp[h];
    const int ec = tid >> 2;
    const int ps = (tid & 3) * 32;
    #pragma unroll
    for (int pass = 0; pass < 2; ++pass) {
        if (wn == pass) {
            #pragma unroll
            for (int rb = 0; rb < 4; ++rb) {
                int p = wm * 64 + rb * 16 + quad * 4;
                #pragma unroll
                for (int nb = 0; nb < 4; ++nb) {
                    int cloc = nb * 16 + m;
                    *(f32x4*)(Ep + cloc * EP_STRIDE + p) = acc[rb][nb];
                }
            }
        }
        __syncthreads();
        {
            int cg = pass * 64 + ec;
            int b  = cg & 7;
            int i  = i0 + (cg >> 3);
            long base = ((long)b * H + h) * L + (long)i * TILE + ps;
            const float* ep = Ep + ec * EP_STRIDE + ps;
            const float* us = u + base;
            if (cplx) {
                if (2 * (base + 32) <= out_floats) {
                    float4* o = (float4*)(outf + 2 * base);
                    #pragma unroll
                    for (int k4 = 0; k4 < 8; ++k4) {
                        float4 uv = ((const float4*)us)[k4];
                        float4 ev = *(const float4*)(ep + k4 * 4);
                        float4 o1, o2;
                        o1.x = ev.x + Dh * uv.x; o1.y = 0.f;
                        o1.z = ev.y + Dh * uv.y; o1.w = 0.f;
                        o2.x = ev.z + Dh * uv.z; o2.y = 0.f;
                        o2.z = ev.w + Dh * uv.w; o2.w = 0.f;
                        o[k4 * 2]     = o1;
                        o[k4 * 2 + 1] = o2;
                    }
                }
            } else {
                if (base + 32 <= out_floats) {
                    float4* o = (float4*)(outf + base);
                    #pragma unroll
                    for (int k4 = 0; k4 < 8; ++k4) {
                        float4 uv = ((const float4*)us)[k4];
                        float4 ev = *(const float4*)(ep + k4 * 4);
                        float4 ov;
                        ov.x = ev.x + Dh * uv.x;
                        ov.y = ev.y + Dh * uv.y;
                        ov.z = ev.z + Dh * uv.z;
                        ov.w = ev.w + Dh * uv.w;
                        o[k4] = ov;
                    }
                }
            }
        }
        __syncthreads();
    }
}

extern "C" void kernel_launch(void* const* d_in, const int* in_sizes, int n_in,
                              void* d_out, int out_size, void* d_ws, size_t ws_size,
                              hipStream_t stream) {
    const float* u  = (const float*)d_in[0];
    const float* Kc = (const float*)d_in[1];
    const float* Dp = (const float*)d_in[2];
    const int H = in_sizes[2];
    const int L = in_sizes[1] / H;          // 8192
    const int G = L / (TILE * IGRP);        // 4
    const int RS = L + 272;
    const int cplx = (out_size >= 2 * in_sizes[0]) ? 1 : 0;

    const size_t kr2_bytes = (size_t)H * 2 * RS * 2;
    const int tier = (ws_size >= kr2_bytes) ? 1 : 0;
    unsigned short* KR2 = (unsigned short*)d_ws;

    if (tier) {
        dim3 gk((RS / 4 + 255) / 256, 2, H);
        build_KR2<<<gk, 256, 0, stream>>>(Kc, KR2, L, RS);
        conv_main_t1<<<H * G, 256, 0, stream>>>(u, Dp, KR2, (float*)d_out,
                                                H, L, G, RS, cplx, (long)out_size);
    } else {
        conv_main_t0<<<H * G, 256, 0, stream>>>(u, Kc, Dp, (float*)d_out,
                                                H, L, G, cplx, (long)out_size);
    }
}

// Round 10
// 239.594 us; speedup vs baseline: 1.0953x; 1.0953x over previous
//
#include <hip/hip_runtime.h>

// Causal Toeplitz-conv GEMM. y[b,h,n] = sum_{m<=n} u[b,h,m]*K[h,n-m] + D[h]*u[b,h,n]
// Out complex64 interleaved (re,0). Block=(h, 16 tiles of 128), 4 waves (2x2),
// wave 64x64 via 4x4 x v_mfma_f32_16x16x32_bf16.
// FINAL = R7 (session best: conv 161us, bench 242.3us; vs 305us at session
// start). The two wins: (1) R3's fixed-overhead shave + setprio; (2) KR2 —
// the Toeplitz shift copies reduced 8->2 rows (shift s -> row s&1, byte
// offset -4*(s>>1); per-lane dwordx4 needs only 4B alignment), shrinking the
// A working set 34.6MB -> 8.7MB = 1.08MB/XCD < 4MB L2. A-loads became
// L2-resident in a latency-bound loop: conv 205 -> 161 (-21%).
// Falsified levers (kept OUT deliberately): barrier-halving/2-step rounds
// (R4, R8: VALUBusy down 40%, wall unchanged); tier0 LDS K-staging (R5:
// +bank conflicts, +VALU, slower); 4 waves/SIMD reg diet (R6, R9: same-step
// A-loads expose ~13us that extra waves cannot hide - all waves hit the
// same dependency at the same barrier phase); deeper A dbuf (R2: register
// cliff at (256,3), compiler spills). The 5+5 A split + afn[5] cross-step
// prefetch is the register-feasible pipelining optimum.
// u staged f32->bf16: load issued at iter top AFTER the A block (R1 lesson:
// a u-miss ahead of A in the VM FIFO head-of-line-blocks A's vmcnt waits),
// packed at the post-compute commit. SLOTS=17 sliding window; tb0 boundary
// mask (register-free). LDS row stride 136 shorts (conflict-minimal,
// measured 8.9e6 vs 6.1e7 at 128).

#define TILE 128
#define IGRP 16
#define SLOTS 17
#define BROW 136                        // shorts per (slot,b) row (128+8)
#define SLOT_STRIDE (8 * BROW)          // 1088 shorts
#define BS_SHORTS (SLOTS * SLOT_STRIDE) // 18496
#define KRC_STRIDE 264                  // tier0 LDS K row (shorts)
#define KRC_BUF (8 * KRC_STRIDE)        // 2112 shorts per buffer
#define EP_STRIDE 132

typedef short bf16x8 __attribute__((ext_vector_type(8)));
typedef float f32x4 __attribute__((ext_vector_type(4)));

__device__ __forceinline__ unsigned short f2bf(float f) {
    unsigned int u = __float_as_uint(f);
    u = (u + 0x7fffu + ((u >> 16) & 1u)) >> 16;  // RNE
    return (unsigned short)u;
}

// KR2[h][r][x] = bf16(K[h][L-1-(x-r)]) for x-r in [0,L), else 0.  r in 0..1.
// 4 shorts per thread, 8B stores.
__global__ __launch_bounds__(256) void build_KR2(
    const float* __restrict__ K, unsigned short* __restrict__ KR2, int L, int RS) {
    int x0 = (blockIdx.x * 256 + threadIdx.x) * 4;
    int r = blockIdx.y;
    long h = blockIdx.z;
    if (x0 >= RS) return;
    const float* Kh = K + h * (long)L;
    unsigned short s[4];
    #pragma unroll
    for (int j = 0; j < 4; ++j) {
        int t = x0 + j - r;
        s[j] = (t >= 0 && t < L) ? f2bf(Kh[L - 1 - t]) : (unsigned short)0;
    }
    uint2 w;
    w.x = s[0] | ((unsigned)s[1] << 16);
    w.y = s[2] | ((unsigned)s[3] << 16);
    *(uint2*)(KR2 + (h * 2 + r) * (long)RS + x0) = w;
}

template <int UK>
__global__ __launch_bounds__(256, 3) void conv_main(
    const float* __restrict__ u, const float* __restrict__ Kc,
    const float* __restrict__ Dp, const unsigned short* __restrict__ KR2,
    float* __restrict__ outf, int H, int L, int G, int RS, int cplx, long out_floats)
{
    __shared__ __align__(16) char smem[UK ? (BS_SHORTS * 2) : (BS_SHORTS * 2 + 2 * KRC_BUF * 2)];
    unsigned short* Bs = (unsigned short*)smem;
    unsigned short* Krc = (unsigned short*)(smem + BS_SHORTS * 2);  // tier0 only
    float* Ep = (float*)smem;

    const int tid  = threadIdx.x;
    const int lane = tid & 63;
    const int wv   = tid >> 6;
    const int wm   = wv >> 1;
    const int wn   = wv & 1;
    const int m    = lane & 15;
    const int quad = lane >> 4;

    const int bx = blockIdx.x;
    const int h  = bx % H;
    const int g  = (G - 1) - (bx / H);  // big groups first
    const int i0 = g * IGRP;
    const int dmax = i0 + IGRP - 1;

    const int rA = (m + 1) & 7;
    const int t0b = 127 - wm * 64 - m + quad * 8;   // t0 base (rb=0,kc=0)
    const int cB = (m & 7) * BROW + quad * 8;       // shorts

    // A source pointer (UK=1): byte addr into KR2, slides -256 B per step.
    // Shift rA lives in row rA&1 at byte offset -4*(rA>>1) (4B-aligned; the
    // value at x' in row rA&1 equals K[L-1-(x-rA)] since x'-(rA&1) == x-rA).
    const char* pA = (const char*)(KR2 + ((long)(h * 2 + (rA & 1))) * RS)
                   + 2 * ((long)(L - TILE) + t0b + rA) - 4 * (rA >> 1);
    // A source (UK=0): LDS Krc byte offset
    const int cAb = 2 * (rA * KRC_STRIDE + t0b + rA);

    // tier0 K-staging constants (5 chunks cover 1056 u32)
    int ldsK[5], taK[5];
    bool vK[5];
    if (UK == 0) {
        #pragma unroll
        for (int p = 0; p < 5; ++p) {
            int wi = tid + p * 256;
            vK[p] = wi < 1056;
            int rp = vK[p] ? (wi / 132) : 0;
            int tp = (wi - rp * 132) * 2;
            ldsK[p] = rp * KRC_STRIDE + tp;
            taK[p] = vK[p] ? (tp - rp) : -1000;
        }
    }
    const float* Kfrow = Kc + (long)h * L;

    // B staging: one (b-row, 4-float) chunk per thread
    const int bb = tid >> 5;
    const int q8 = (tid & 31) * 4;
    const long ubase = ((long)bb * H + h) * L;

    f32x4 acc[4][4];
    {
        f32x4 z = {0.f, 0.f, 0.f, 0.f};
        #pragma unroll
        for (int a = 0; a < 4; ++a)
            #pragma unroll
            for (int b = 0; b < 4; ++b) acc[a][b] = z;
    }

    int sc4[4];
    #pragma unroll
    for (int nb = 0; nb < 4; ++nb) {
        int il = wn * 8 + nb * 2 + (m >> 3);
        sc4[nb] = (i0 + il) % SLOTS;
    }
    int slotw = (i0 >= 1) ? ((i0 - 1) % SLOTS) : (SLOTS - 1);

    // ---- prologue: stage 16 window tiles (f32 -> bf16); tier0 also Krc[0] ----
    #pragma unroll
    for (int batch = 0; batch < 2; ++batch) {
        uint2 a8[8];
        #pragma unroll
        for (int q = 0; q < 8; ++q) {
            int j = i0 + batch * 8 + q;
            float4 v = *(const float4*)(u + ubase + (long)j * TILE + q8);
            a8[q].x = f2bf(v.x) | ((unsigned)f2bf(v.y) << 16);
            a8[q].y = f2bf(v.z) | ((unsigned)f2bf(v.w) << 16);
        }
        #pragma unroll
        for (int q = 0; q < 8; ++q) {
            int j = i0 + batch * 8 + q;
            *(uint2*)(Bs + (j % SLOTS) * SLOT_STRIDE + bb * BROW + q8) = a8[q];
        }
    }
    if (UK == 0) {
        #pragma unroll
        for (int p = 0; p < 5; ++p) {
            if (vK[p]) {
                unsigned int s0 = 0, s1 = 0;
                int ta = taK[p];
                int ka = 127 - ta;
                if (ta >= 0 && ta < 256 && ka >= 0) s0 = f2bf(Kfrow[ka]);
                if (ta + 1 >= 0 && ta + 1 < 256 && (ka - 1) >= 0) s1 = f2bf(Kfrow[ka - 1]);
                *(unsigned int*)(Krc + ldsK[p]) = s0 | (s1 << 16);
            }
        }
    }
    bf16x8 af[10], afn[5] = {};
    if (UK) {
        #pragma unroll
        for (int o = 0; o < 5; ++o) af[o] = *(const bf16x8*)(pA + (o - 3) * 32);
    }
    __syncthreads();

    const bool tb0 = (m < 8);           // lower-tile lanes (boundary mask)
    const bf16x8 z8 = {};

    // ---- main loop: one barrier per iter ----
    for (int d = 0; d <= dmax; ++d) {
        const int dn = d + 1;
        const int jn = i0 - 1 - d;

        // A frags: current-iter high half (UK1) or all from LDS (UK0)
        if (UK) {
            #pragma unroll
            for (int o = 5; o < 10; ++o) af[o] = *(const bf16x8*)(pA + (o - 3) * 32);
        } else {
            const char* Ab = (const char*)Krc + (d & 1) * (KRC_BUF * 2) + cAb;
            #pragma unroll
            for (int o = 0; o < 10; ++o) af[o] = *(const bf16x8*)(Ab + (o - 3) * 32);
        }

        // stage next B tile: ISSUE the f32 load now, pack AFTER compute
        float4 fv = {0.f, 0.f, 0.f, 0.f};
        if (jn >= 0)
            fv = *(const float4*)(u + ubase + (long)jn * TILE + q8);

        // A prefetch for next iter (no barrier dependency)
        if (UK) {
            if (d < dmax) {
                #pragma unroll
                for (int o = 0; o < 5; ++o) afn[o] = *(const bf16x8*)(pA - 256 + (o - 3) * 32);
            }
        }
        // tier0: K window values for next iter (guarded f32)
        unsigned int kv[5] = {0u, 0u, 0u, 0u, 0u};
        if (UK == 0 && dn <= dmax) {
            #pragma unroll
            for (int p = 0; p < 5; ++p) {
                unsigned int s0 = 0, s1 = 0;
                int ta = taK[p];
                if (vK[p]) {
                    int ka = dn * TILE + 127 - ta;
                    if (ta >= 0 && ta < 256 && ka >= 0) s0 = f2bf(Kfrow[ka]);
                    if (ta + 1 >= 0 && ta + 1 < 256 && (ka - 1) >= 0) s1 = f2bf(Kfrow[ka - 1]);
                }
                kv[p] = s0 | (s1 << 16);
            }
        }

        // ---- compute ----
        const int dlim = d - i0;
        const unsigned short* Bp[4];
        #pragma unroll
        for (int nb = 0; nb < 4; ++nb)
            Bp[nb] = Bs + sc4[nb] * SLOT_STRIDE + cB;

        __builtin_amdgcn_s_setprio(1);
        #pragma unroll
        for (int kc = 0; kc < 4; ++kc) {
            #pragma unroll
            for (int nb = 0; nb < 4; ++nb) {
                const int nbg = wn * 4 + nb;
                if (2 * nbg + 1 >= dlim) {
                    bf16x8 bfr = *(const bf16x8*)(Bp[nb] + kc * 32);
                    // boundary col mask: col<0 at 2nbg+1==dlim  <=>  m>>3==0
                    if (2 * nbg + 1 == dlim) bfr = tb0 ? z8 : bfr;
                    acc[0][nb] = __builtin_amdgcn_mfma_f32_16x16x32_bf16(af[3 + 2 * kc], bfr, acc[0][nb], 0, 0, 0);
                    acc[1][nb] = __builtin_amdgcn_mfma_f32_16x16x32_bf16(af[2 + 2 * kc], bfr, acc[1][nb], 0, 0, 0);
                    acc[2][nb] = __builtin_amdgcn_mfma_f32_16x16x32_bf16(af[1 + 2 * kc], bfr, acc[2][nb], 0, 0, 0);
                    acc[3][nb] = __builtin_amdgcn_mfma_f32_16x16x32_bf16(af[0 + 2 * kc], bfr, acc[3][nb], 0, 0, 0);
                }
            }
        }
        __builtin_amdgcn_s_setprio(0);

        // commit staged data for next iter (pack happens HERE, behind the MFMAs)
        if (UK == 0 && dn <= dmax) {
            unsigned short* Kw = Krc + (dn & 1) * KRC_BUF;
            #pragma unroll
            for (int p = 0; p < 5; ++p)
                if (vK[p]) *(unsigned int*)(Kw + ldsK[p]) = kv[p];
        }
        if (jn >= 0) {
            uint2 bv;
            bv.x = f2bf(fv.x) | ((unsigned)f2bf(fv.y) << 16);
            bv.y = f2bf(fv.z) | ((unsigned)f2bf(fv.w) << 16);
            *(uint2*)(Bs + slotw * SLOT_STRIDE + bb * BROW + q8) = bv;
        }

        slotw = slotw ? slotw - 1 : SLOTS - 1;
        #pragma unroll
        for (int nb = 0; nb < 4; ++nb)
            sc4[nb] = sc4[nb] ? sc4[nb] - 1 : SLOTS - 1;
        if (UK) {
            #pragma unroll
            for (int o = 0; o < 5; ++o) af[o] = afn[o];
            pA -= 256;
        }
        __syncthreads();
    }

    // ---- epilogue: LDS transpose (2 passes), skip-add, store ----
    const float Dh = Dp[h];
    const int ec = tid >> 2;
    const int ps = (tid & 3) * 32;
    #pragma unroll
    for (int pass = 0; pass < 2; ++pass) {
        if (wn == pass) {
            #pragma unroll
            for (int rb = 0; rb < 4; ++rb) {
                int p = wm * 64 + rb * 16 + quad * 4;  // C/D row = quad*4+reg
                #pragma unroll
                for (int nb = 0; nb < 4; ++nb) {
                    int cloc = nb * 16 + m;            // C/D col = lane&15
                    *(f32x4*)(Ep + cloc * EP_STRIDE + p) = acc[rb][nb];
                }
            }
        }
        __syncthreads();
        {
            int cg = pass * 64 + ec;
            int b  = cg & 7;
            int i  = i0 + (cg >> 3);
            long base = ((long)b * H + h) * L + (long)i * TILE + ps;
            const float* ep = Ep + ec * EP_STRIDE + ps;
            const float* us = u + base;
            if (cplx) {
                if (2 * (base + 32) <= out_floats) {
                    float4* o = (float4*)(outf + 2 * base);
                    #pragma unroll
                    for (int k4 = 0; k4 < 8; ++k4) {
                        float4 uv = ((const float4*)us)[k4];
                        float4 ev = *(const float4*)(ep + k4 * 4);
                        float4 o1, o2;
                        o1.x = ev.x + Dh * uv.x; o1.y = 0.f;
                        o1.z = ev.y + Dh * uv.y; o1.w = 0.f;
                        o2.x = ev.z + Dh * uv.z; o2.y = 0.f;
                        o2.z = ev.w + Dh * uv.w; o2.w = 0.f;
                        o[k4 * 2]     = o1;
                        o[k4 * 2 + 1] = o2;
                    }
                }
            } else {
                if (base + 32 <= out_floats) {
                    float4* o = (float4*)(outf + base);
                    #pragma unroll
                    for (int k4 = 0; k4 < 8; ++k4) {
                        float4 uv = ((const float4*)us)[k4];
                        float4 ev = *(const float4*)(ep + k4 * 4);
                        float4 ov;
                        ov.x = ev.x + Dh * uv.x;
                        ov.y = ev.y + Dh * uv.y;
                        ov.z = ev.z + Dh * uv.z;
                        ov.w = ev.w + Dh * uv.w;
                        o[k4] = ov;
                    }
                }
            }
        }
        __syncthreads();
    }
}

extern "C" void kernel_launch(void* const* d_in, const int* in_sizes, int n_in,
                              void* d_out, int out_size, void* d_ws, size_t ws_size,
                              hipStream_t stream) {
    const float* u  = (const float*)d_in[0];
    const float* Kc = (const float*)d_in[1];
    const float* Dp = (const float*)d_in[2];
    const int H = in_sizes[2];
    const int L = in_sizes[1] / H;          // 8192
    const int G = L / (TILE * IGRP);        // 4
    const int RS = L + 272;
    const int cplx = (out_size >= 2 * in_sizes[0]) ? 1 : 0;

    const size_t kr2_bytes = (size_t)H * 2 * RS * 2;
    const int tier = (ws_size >= kr2_bytes) ? 1 : 0;
    unsigned short* KR2 = (unsigned short*)d_ws;

    if (tier) {
        dim3 gk((RS / 4 + 255) / 256, 2, H);
        build_KR2<<<gk, 256, 0, stream>>>(Kc, KR2, L, RS);
        conv_main<1><<<H * G, 256, 0, stream>>>(u, Kc, Dp, KR2, (float*)d_out,
                                                H, L, G, RS, cplx, (long)out_size);
    } else {
        conv_main<0><<<H * G, 256, 0, stream>>>(u, Kc, Dp, KR2, (float*)d_out,
                                                H, L, G, RS, cplx, (long)out_size);
    }
}